// Round 2
// baseline (648.015 us; speedup 1.0000x reference)
//
#include <hip/hip_runtime.h>

// ---------------------------------------------------------------------------
// MultiHeadAttention: B=2, T=2048, C=2048, H=16, D=128. fp32 in, fp32 out.
// Internals: bf16 MFMA, fp32 accum. ws >= 92.3MB confirmed in round 6.
// R7: GEMMs use global_load_lds (m97); attention 128-q-tile, 8 waves/block.
// R8: attn rework — paired q-tiles (uniform 33 tile-units/block), double-
//     buffered async global_load_lds staging (1 barrier/tile), XOR-swizzled
//     K/V/P LDS (8 lanes/bank-group on ds_read_b128 = conflict floor).
// R9: fix K staging chunk index (16 chunks/row, not 8 — R8 read rows [0,128)).
// ---------------------------------------------------------------------------

typedef __attribute__((ext_vector_type(8))) short short8;
typedef __attribute__((ext_vector_type(4))) float floatx4;
typedef __attribute__((ext_vector_type(4))) unsigned int uint4v;

#define MFMA16(a, b, c) __builtin_amdgcn_mfma_f32_16x16x32_bf16(a, b, c, 0, 0, 0)

__device__ inline unsigned short f2bf(float f) {
    union { float f; unsigned int i; } v; v.f = f;
    unsigned int r = v.i + 0x7fff + ((v.i >> 16) & 1);   // round-nearest-even
    return (unsigned short)(r >> 16);
}

// async 16B global->LDS (m97). Per-lane lds ptrs must be base + lane*16.
__device__ inline void gl2lds16(const unsigned short* g, unsigned short* l) {
    __builtin_amdgcn_global_load_lds(
        (const __attribute__((address_space(1))) unsigned int*)g,
        (__attribute__((address_space(3))) unsigned int*)l, 16, 0, 0);
}

// ---------------- fp32 -> bf16 bulk convert (8 elems/thread) -----------------
__global__ __launch_bounds__(256) void cvt_k(const float* __restrict__ in,
                                             unsigned short* __restrict__ out, int n) {
    int i = (blockIdx.x * 256 + threadIdx.x) * 8;
    if (i + 7 < n) {
        float4 v0 = *(const float4*)(&in[i]);
        float4 v1 = *(const float4*)(&in[i + 4]);
        ushort4 o0, o1;
        o0.x = f2bf(v0.x); o0.y = f2bf(v0.y); o0.z = f2bf(v0.z); o0.w = f2bf(v0.w);
        o1.x = f2bf(v1.x); o1.y = f2bf(v1.y); o1.z = f2bf(v1.z); o1.w = f2bf(v1.w);
        *(ushort4*)(&out[i])     = o0;
        *(ushort4*)(&out[i + 4]) = o1;
    } else {
        for (int j = i; j < n; j++) out[j] = f2bf(in[j]);
    }
}

// ---------- fused fp32 transpose+cvt: in[R][Cc] f32 -> out[Cc][R] bf16 -------
__global__ __launch_bounds__(256) void transpose_f2b_k(const float* __restrict__ in,
                                                       unsigned short* __restrict__ out,
                                                       int R, int Cc) {
    __shared__ unsigned short tile[32][33];
    int ct = blockIdx.x * 32;
    int rt = blockIdx.y * 32;
    int tx = threadIdx.x & 31;
    int ty = threadIdx.x >> 5;
#pragma unroll
    for (int i = 0; i < 32; i += 8)
        tile[ty + i][tx] = f2bf(in[(size_t)(rt + ty + i) * Cc + ct + tx]);
    __syncthreads();
#pragma unroll
    for (int i = 0; i < 32; i += 8)
        out[(size_t)(ct + ty + i) * R + rt + tx] = tile[tx][ty + i];
}

// ------------- per-head V transpose: qkv[b,t,2,h,:] -> VT[bh][d][t] ----------
__global__ __launch_bounds__(256) void transpose_v_k(const unsigned short* __restrict__ qkv,
                                                     unsigned short* __restrict__ VT) {
    __shared__ unsigned short tile[32][33];
    int t0 = blockIdx.x * 32;
    int d0 = blockIdx.y * 32;
    int bh = blockIdx.z;
    int b = bh >> 4, h = bh & 15;
    int tx = threadIdx.x & 31;
    int ty = threadIdx.x >> 5;
#pragma unroll
    for (int i = 0; i < 32; i += 8)
        tile[ty + i][tx] =
            qkv[((size_t)(b * 2048 + t0 + ty + i) * 3 + 2) * 2048 + h * 128 + d0 + tx];
    __syncthreads();
#pragma unroll
    for (int i = 0; i < 32; i += 8)
        VT[((size_t)bh * 128 + d0 + ty + i) * 2048 + t0 + tx] = tile[tx][ty + i];
}

// ---------------- RoPE in place on q/k parts of qkv (fp32 cos/sin) -----------
__global__ __launch_bounds__(256) void rotary_k(unsigned short* qkv,
                                                const float* __restrict__ cosT,
                                                const float* __restrict__ sinT) {
    int idx = blockIdx.x * 256 + threadIdx.x;
    int d    = idx & 63;
    int h    = (idx >> 6) & 15;
    int part = (idx >> 10) & 1;
    int t    = (idx >> 11) & 2047;
    int b    = idx >> 22;
    size_t base = ((size_t)(b * 2048 + t) * 3 + part) * 2048 + h * 128;
    float c = cosT[t * 64 + d];
    float s = sinT[t * 64 + d];
    union { unsigned int i; float f; } u1, u2;
    u1.i = ((unsigned int)qkv[base + d]) << 16;
    u2.i = ((unsigned int)qkv[base + d + 64]) << 16;
    float x1 = u1.f, x2 = u2.f;
    qkv[base + d]      = f2bf(x1 * c - x2 * s);
    qkv[base + d + 64] = f2bf(x2 * c + x1 * s);
}

// ---- GEMM (m97): C[M,N] = A[M,K](bf16) * Bt[N,K]^T(bf16), async staging ----
template <bool OUTF32>
__global__ __launch_bounds__(256) void gemm_bt(const unsigned short* __restrict__ A, long lda,
                                               const unsigned short* __restrict__ Bt,
                                               void* __restrict__ Co, long ldc,
                                               int M, int N, int K) {
    __shared__ unsigned short a_lds[128 * 32];   // unpadded: lane-contiguous for DMA
    __shared__ unsigned short b_lds[128 * 32];
    int m0 = blockIdx.y * 128, n0 = blockIdx.x * 128;
    int tid = threadIdx.x;
    int lane = tid & 63, w = tid >> 6;
    int wm = (w >> 1) * 64, wn = (w & 1) * 64;
    int lr = lane & 15, quad = lane >> 4, lk = quad * 8;

    floatx4 acc[4][4];
    floatx4 zero4 = {0.f, 0.f, 0.f, 0.f};
#pragma unroll
    for (int i = 0; i < 4; i++)
#pragma unroll
        for (int j = 0; j < 4; j++) acc[i][j] = zero4;

    for (int k0 = 0; k0 < K; k0 += 32) {
        // 16B chunks: c in [0,512); row = c>>2, seg = c&3. Lane-contiguous LDS.
#pragma unroll
        for (int i = 0; i < 2; i++) {
            int c = w * 128 + i * 64 + lane;
            int row = c >> 2, seg = (c & 3) * 8;
            gl2lds16(&A[(size_t)(m0 + row) * lda + k0 + seg], &a_lds[c * 8]);
            gl2lds16(&Bt[(size_t)(n0 + row) * K + k0 + seg], &b_lds[c * 8]);
        }
        __syncthreads();
        short8 af[4], bfr[4];
#pragma unroll
        for (int i = 0; i < 4; i++)
            af[i] = *(const short8*)(&a_lds[(wm + i * 16 + lr) * 32 + lk]);
#pragma unroll
        for (int j = 0; j < 4; j++)
            bfr[j] = *(const short8*)(&b_lds[(wn + j * 16 + lr) * 32 + lk]);
#pragma unroll
        for (int i = 0; i < 4; i++)
#pragma unroll
            for (int j = 0; j < 4; j++)
                acc[i][j] = MFMA16(af[i], bfr[j], acc[i][j]);
        __syncthreads();
    }
#pragma unroll
    for (int i = 0; i < 4; i++)
#pragma unroll
        for (int j = 0; j < 4; j++)
#pragma unroll
            for (int r = 0; r < 4; r++) {
                int row = m0 + wm + i * 16 + quad * 4 + r;
                int col = n0 + wn + j * 16 + lr;
                if (OUTF32)
                    ((float*)Co)[(size_t)row * ldc + col] = acc[i][j][r];
                else
                    ((unsigned short*)Co)[(size_t)row * ldc + col] = f2bf(acc[i][j][r]);
            }
}

// ---------------------------------------------------------------------------
// attention core: one 16-q-row group vs one 64-key staged tile.
// LDS layouts are XOR-swizzled at 16B granularity: slot' = slot ^ (row & 7).
// ---------------------------------------------------------------------------
__device__ __forceinline__ void attn_core(const short8 (&qf)[4], floatx4 (&o_acc)[8],
                                          float (&m_i)[4], float (&l_i)[4],
                                          const unsigned short* __restrict__ kb_lds,
                                          const unsigned short* __restrict__ vb_lds,
                                          unsigned short* __restrict__ p_w,
                                          int qrow0, int tk0, int lr, int quad) {
    floatx4 zero4 = {0.f, 0.f, 0.f, 0.f};
    const float scale = 0.08838834764831845f;

    floatx4 s[4];
#pragma unroll
    for (int n = 0; n < 4; n++) {
        s[n] = zero4;
        int key = n * 16 + lr;                     // K row this lane feeds as B-frag
#pragma unroll
        for (int c = 0; c < 4; c++) {
            short8 kb = *(const short8*)(&kb_lds[key * 128 + (((c * 4 + quad) ^ (key & 7)) * 8)]);
            s[n] = MFMA16(qf[c], kb, s[n]);
        }
    }

    float rmax[4];
#pragma unroll
    for (int r = 0; r < 4; r++) {
        int tqr = qrow0 + quad * 4 + r;
        float mx = -1e30f;
#pragma unroll
        for (int n = 0; n < 4; n++) {
            int tk = tk0 + n * 16 + lr;
            float sv = s[n][r] * scale;
            sv = (tk > tqr) ? -1e30f : sv;
            s[n][r] = sv;
            mx = fmaxf(mx, sv);
        }
        rmax[r] = mx;
    }
#pragma unroll
    for (int off = 1; off < 16; off <<= 1)
#pragma unroll
        for (int r = 0; r < 4; r++)
            rmax[r] = fmaxf(rmax[r], __shfl_xor(rmax[r], off, 64));

    float alpha[4], rsum[4];
#pragma unroll
    for (int r = 0; r < 4; r++) {
        float mn = fmaxf(m_i[r], rmax[r]);
        alpha[r] = __expf(m_i[r] - mn);
        m_i[r] = mn;
        rsum[r] = 0.f;
    }
#pragma unroll
    for (int n = 0; n < 4; n++)
#pragma unroll
        for (int r = 0; r < 4; r++) {
            float p = __expf(s[n][r] - m_i[r]);
            rsum[r] += p;
            int q = quad * 4 + r;                  // swizzled scalar store
            p_w[q * 64 + (((n * 2 + (lr >> 3)) ^ (q & 7)) * 8) + (lr & 7)] = f2bf(p);
        }
#pragma unroll
    for (int off = 1; off < 16; off <<= 1)
#pragma unroll
        for (int r = 0; r < 4; r++)
            rsum[r] += __shfl_xor(rsum[r], off, 64);
#pragma unroll
    for (int r = 0; r < 4; r++) l_i[r] = l_i[r] * alpha[r] + rsum[r];

#pragma unroll
    for (int dt = 0; dt < 8; dt++)
#pragma unroll
        for (int r = 0; r < 4; r++) o_acc[dt][r] *= alpha[r];

    short8 pa[2];
#pragma unroll
    for (int kc = 0; kc < 2; kc++)
        pa[kc] = *(const short8*)(&p_w[lr * 64 + (((kc * 4 + quad) ^ (lr & 7)) * 8)]);
#pragma unroll
    for (int dt = 0; dt < 8; dt++) {
        int d = dt * 16 + lr;
#pragma unroll
        for (int kc = 0; kc < 2; kc++) {
            short8 vb = *(const short8*)(&vb_lds[d * 64 + (((kc * 4 + quad) ^ (d & 7)) * 8)]);
            o_acc[dt] = MFMA16(pa[kc], vb, o_acc[dt]);
        }
    }
}

// -------- flash attention: paired q-tiles (64+64 rows), 4 waves, dbuf -------
__global__ __launch_bounds__(256, 2) void attn_fast(unsigned short* qkv,
                                                    const unsigned short* __restrict__ VT) {
    const int T = 2048, Cc = 2048, Dd = 128;
    int a = blockIdx.x;                    // 0..15
    int hi = 31 - a, lo = a;               // paired 64-row q-tiles: uniform work
    int bh = blockIdx.y;
    int b = bh >> 4, h = bh & 15;
    int tid = threadIdx.x, lane = tid & 63, w = tid >> 6;   // w in [0,4)
    int lr = lane & 15, quad = lane >> 4, lk = quad * 8;
    int t0_hi = hi * 64, t0_lo = lo * 64;

    __shared__ __align__(16) unsigned short k_lds[2][64 * 128];   // [key][d] swz
    __shared__ __align__(16) unsigned short v_lds[2][128 * 64];   // [d][key] swz
    __shared__ __align__(16) unsigned short p_lds[4][16 * 64];    // per-wave P swz

    // Q fragments for both q-tiles (A-frag: row=lr, k=c*32+quad*8+j)
    short8 qf_hi[4], qf_lo[4];
    {
        size_t qr_hi = (size_t)(b * T + t0_hi + w * 16 + lr) * 3 * Cc + h * Dd;
        size_t qr_lo = (size_t)(b * T + t0_lo + w * 16 + lr) * 3 * Cc + h * Dd;
#pragma unroll
        for (int c = 0; c < 4; c++) {
            qf_hi[c] = *(const short8*)(&qkv[qr_hi + c * 32 + lk]);
            qf_lo[c] = *(const short8*)(&qkv[qr_lo + c * 32 + lk]);
        }
    }

    floatx4 o_hi[8], o_lo[8];
    floatx4 zero4 = {0.f, 0.f, 0.f, 0.f};
#pragma unroll
    for (int i = 0; i < 8; i++) { o_hi[i] = zero4; o_lo[i] = zero4; }
    float m_hi[4], l_hi[4], m_lo[4], l_lo[4];
#pragma unroll
    for (int r = 0; r < 4; r++) {
        m_hi[r] = -1e30f; l_hi[r] = 0.f;
        m_lo[r] = -1e30f; l_lo[r] = 0.f;
    }

    // async stage of one 64-key K tile + V^T tile into buffer `buf`.
    // LDS dest is linear (chunk c at byte c*16); the swizzle is applied by
    // permuting the global source chunk (slot = slot' ^ (row&7)) per m173.
    // K tile: 64 rows x 128 elems = 16 chunks/row. V tile: 128 rows x 64 = 8/row.
    auto stage = [&](int buf, int kt) {
        int tk0 = kt * 64;
#pragma unroll
        for (int i = 0; i < 4; i++) {
            int c = i * 256 + tid;             // 1024 chunks of 16B
            int key = c >> 4, sp = c & 15;     // R9 fix: 16 chunks per K row
            int slot = sp ^ (key & 7);
            gl2lds16(&qkv[((size_t)(b * T + tk0 + key) * 3 + 1) * Cc + h * Dd + slot * 8],
                     &k_lds[buf][c * 8]);
        }
#pragma unroll
        for (int i = 0; i < 4; i++) {
            int c = i * 256 + tid;
            int d = c >> 3, sp = c & 7;
            int slot = sp ^ (d & 7);
            gl2lds16(&VT[((size_t)bh * Dd + d) * T + tk0 + slot * 8],
                     &v_lds[buf][c * 8]);
        }
    };

    int nkt = hi + 1;
    stage(0, 0);
    __syncthreads();                           // implicit vmcnt(0) drain
    int cur = 0;
    for (int kt = 0; kt < nkt; kt++) {
        if (kt + 1 < nkt) stage(cur ^ 1, kt + 1);   // in flight across compute
        int tk0 = kt * 64;
        attn_core(qf_hi, o_hi, m_hi, l_hi, k_lds[cur], v_lds[cur], p_lds[w],
                  t0_hi + w * 16, tk0, lr, quad);
        if (kt <= lo)                          // block-uniform branch
            attn_core(qf_lo, o_lo, m_lo, l_lo, k_lds[cur], v_lds[cur], p_lds[w],
                      t0_lo + w * 16, tk0, lr, quad);
        __syncthreads();                       // drains next-tile staging too
        cur ^= 1;
    }

    // epilogue: O over q slots -> qkv[b, t, 0, h, d]
#pragma unroll
    for (int dt = 0; dt < 8; dt++)
#pragma unroll
        for (int r = 0; r < 4; r++) {
            int col = dt * 16 + lr;
            int row_h = t0_hi + w * 16 + quad * 4 + r;
            qkv[(size_t)(b * T + row_h) * 3 * Cc + h * Dd + col] =
                f2bf(o_hi[dt][r] * (1.0f / l_hi[r]));
            int row_l = t0_lo + w * 16 + quad * 4 + r;
            qkv[(size_t)(b * T + row_l) * 3 * Cc + h * Dd + col] =
                f2bf(o_lo[dt][r] * (1.0f / l_lo[r]));
        }
}

// ---------------------------------------------------------------------------
extern "C" void kernel_launch(void* const* d_in, const int* in_sizes, int n_in,
                              void* d_out, int out_size, void* d_ws, size_t ws_size,
                              hipStream_t stream) {
    const float* x    = (const float*)d_in[0];
    const float* wqkv = (const float*)d_in[1];
    const float* wout = (const float*)d_in[2];
    const float* cosT = (const float*)d_in[3];
    const float* sinT = (const float*)d_in[4];
    float* out = (float*)d_out;

    unsigned short* qkv = (unsigned short*)d_ws;          // 48 MiB
    const size_t QKV = 25165824, XBF = 8388608;
    unsigned short* xbf = qkv + QKV;                      // 16 MiB; VT overlays after gemm1
    unsigned short* wTq = xbf + XBF;                      // 24 MiB; wTo overlays after gemm1
    unsigned short* VT  = xbf;
    unsigned short* wTo = wTq;

    cvt_k<<<4096, 256, 0, stream>>>(x, xbf, 8388608);
    transpose_f2b_k<<<dim3(192, 64), 256, 0, stream>>>(wqkv, wTq, 2048, 6144);
    gemm_bt<false><<<dim3(48, 32), 256, 0, stream>>>(xbf, 2048, wTq, qkv, 6144,
                                                     4096, 6144, 2048);
    rotary_k<<<32768, 256, 0, stream>>>(qkv, cosT, sinT);
    transpose_f2b_k<<<dim3(64, 64), 256, 0, stream>>>(wout, wTo, 2048, 2048);
    transpose_v_k<<<dim3(64, 4, 32), 256, 0, stream>>>(qkv, VT);
    attn_fast<<<dim3(16, 32), 256, 0, stream>>>(qkv, VT);
    gemm_bt<true><<<dim3(16, 32), 256, 0, stream>>>(qkv, 6144, wTo, out, 2048,
                                                    4096, 2048, 2048);
}

// Round 4
// 502.817 us; speedup vs baseline: 1.2888x; 1.2888x over previous
//
#include <hip/hip_runtime.h>

// ---------------------------------------------------------------------------
// MultiHeadAttention: B=2, T=2048, C=2048, H=16, D=128. fp32 in, fp32 out.
// Internals: bf16 MFMA, fp32 accum. ws >= 92.3MB confirmed in round 6.
// R7: GEMMs use global_load_lds (m97); attention 128-q-tile, 8 waves/block.
// R8/R9: paired-tile + global_load_lds dbuf -> 7x HBM traffic (L2 thrash),
//        306us. REVERTED.
// R10: R7 geometry + T14 async reg-staging + XOR-swizzled K/V LDS.
//      launch_bounds(512,6) risked forced spill (~85 VGPR cap vs ~140 live).
// R11: single reg prefetch buffer (-16 VGPR), launch_bounds(512,4) (128 cap,
//      no spill, 2 blocks/CU). Same T14 overlap, same traffic as R7.
// ---------------------------------------------------------------------------

typedef __attribute__((ext_vector_type(8))) short short8;
typedef __attribute__((ext_vector_type(4))) float floatx4;
typedef __attribute__((ext_vector_type(4))) unsigned int uint4v;

#define MFMA16(a, b, c) __builtin_amdgcn_mfma_f32_16x16x32_bf16(a, b, c, 0, 0, 0)

__device__ inline unsigned short f2bf(float f) {
    union { float f; unsigned int i; } v; v.f = f;
    unsigned int r = v.i + 0x7fff + ((v.i >> 16) & 1);   // round-nearest-even
    return (unsigned short)(r >> 16);
}

// async 16B global->LDS (m97). Per-lane lds ptrs must be base + lane*16.
__device__ inline void gl2lds16(const unsigned short* g, unsigned short* l) {
    __builtin_amdgcn_global_load_lds(
        (const __attribute__((address_space(1))) unsigned int*)g,
        (__attribute__((address_space(3))) unsigned int*)l, 16, 0, 0);
}

// ---------------- fp32 -> bf16 bulk convert (8 elems/thread) -----------------
__global__ __launch_bounds__(256) void cvt_k(const float* __restrict__ in,
                                             unsigned short* __restrict__ out, int n) {
    int i = (blockIdx.x * 256 + threadIdx.x) * 8;
    if (i + 7 < n) {
        float4 v0 = *(const float4*)(&in[i]);
        float4 v1 = *(const float4*)(&in[i + 4]);
        ushort4 o0, o1;
        o0.x = f2bf(v0.x); o0.y = f2bf(v0.y); o0.z = f2bf(v0.z); o0.w = f2bf(v0.w);
        o1.x = f2bf(v1.x); o1.y = f2bf(v1.y); o1.z = f2bf(v1.z); o1.w = f2bf(v1.w);
        *(ushort4*)(&out[i])     = o0;
        *(ushort4*)(&out[i + 4]) = o1;
    } else {
        for (int j = i; j < n; j++) out[j] = f2bf(in[j]);
    }
}

// ---------- fused fp32 transpose+cvt: in[R][Cc] f32 -> out[Cc][R] bf16 -------
__global__ __launch_bounds__(256) void transpose_f2b_k(const float* __restrict__ in,
                                                       unsigned short* __restrict__ out,
                                                       int R, int Cc) {
    __shared__ unsigned short tile[32][33];
    int ct = blockIdx.x * 32;
    int rt = blockIdx.y * 32;
    int tx = threadIdx.x & 31;
    int ty = threadIdx.x >> 5;
#pragma unroll
    for (int i = 0; i < 32; i += 8)
        tile[ty + i][tx] = f2bf(in[(size_t)(rt + ty + i) * Cc + ct + tx]);
    __syncthreads();
#pragma unroll
    for (int i = 0; i < 32; i += 8)
        out[(size_t)(ct + ty + i) * R + rt + tx] = tile[tx][ty + i];
}

// ------------- per-head V transpose: qkv[b,t,2,h,:] -> VT[bh][d][t] ----------
__global__ __launch_bounds__(256) void transpose_v_k(const unsigned short* __restrict__ qkv,
                                                     unsigned short* __restrict__ VT) {
    __shared__ unsigned short tile[32][33];
    int t0 = blockIdx.x * 32;
    int d0 = blockIdx.y * 32;
    int bh = blockIdx.z;
    int b = bh >> 4, h = bh & 15;
    int tx = threadIdx.x & 31;
    int ty = threadIdx.x >> 5;
#pragma unroll
    for (int i = 0; i < 32; i += 8)
        tile[ty + i][tx] =
            qkv[((size_t)(b * 2048 + t0 + ty + i) * 3 + 2) * 2048 + h * 128 + d0 + tx];
    __syncthreads();
#pragma unroll
    for (int i = 0; i < 32; i += 8)
        VT[((size_t)bh * 128 + d0 + ty + i) * 2048 + t0 + tx] = tile[tx][ty + i];
}

// ---------------- RoPE in place on q/k parts of qkv (fp32 cos/sin) -----------
__global__ __launch_bounds__(256) void rotary_k(unsigned short* qkv,
                                                const float* __restrict__ cosT,
                                                const float* __restrict__ sinT) {
    int idx = blockIdx.x * 256 + threadIdx.x;
    int d    = idx & 63;
    int h    = (idx >> 6) & 15;
    int part = (idx >> 10) & 1;
    int t    = (idx >> 11) & 2047;
    int b    = idx >> 22;
    size_t base = ((size_t)(b * 2048 + t) * 3 + part) * 2048 + h * 128;
    float c = cosT[t * 64 + d];
    float s = sinT[t * 64 + d];
    union { unsigned int i; float f; } u1, u2;
    u1.i = ((unsigned int)qkv[base + d]) << 16;
    u2.i = ((unsigned int)qkv[base + d + 64]) << 16;
    float x1 = u1.f, x2 = u2.f;
    qkv[base + d]      = f2bf(x1 * c - x2 * s);
    qkv[base + d + 64] = f2bf(x2 * c + x1 * s);
}

// ---- GEMM (m97): C[M,N] = A[M,K](bf16) * Bt[N,K]^T(bf16), async staging ----
template <bool OUTF32>
__global__ __launch_bounds__(256) void gemm_bt(const unsigned short* __restrict__ A, long lda,
                                               const unsigned short* __restrict__ Bt,
                                               void* __restrict__ Co, long ldc,
                                               int M, int N, int K) {
    __shared__ unsigned short a_lds[128 * 32];   // unpadded: lane-contiguous for DMA
    __shared__ unsigned short b_lds[128 * 32];
    int m0 = blockIdx.y * 128, n0 = blockIdx.x * 128;
    int tid = threadIdx.x;
    int lane = tid & 63, w = tid >> 6;
    int wm = (w >> 1) * 64, wn = (w & 1) * 64;
    int lr = lane & 15, quad = lane >> 4, lk = quad * 8;

    floatx4 acc[4][4];
    floatx4 zero4 = {0.f, 0.f, 0.f, 0.f};
#pragma unroll
    for (int i = 0; i < 4; i++)
#pragma unroll
        for (int j = 0; j < 4; j++) acc[i][j] = zero4;

    for (int k0 = 0; k0 < K; k0 += 32) {
        // 16B chunks: c in [0,512); row = c>>2, seg = c&3. Lane-contiguous LDS.
#pragma unroll
        for (int i = 0; i < 2; i++) {
            int c = w * 128 + i * 64 + lane;
            int row = c >> 2, seg = (c & 3) * 8;
            gl2lds16(&A[(size_t)(m0 + row) * lda + k0 + seg], &a_lds[c * 8]);
            gl2lds16(&Bt[(size_t)(n0 + row) * K + k0 + seg], &b_lds[c * 8]);
        }
        __syncthreads();
        short8 af[4], bfr[4];
#pragma unroll
        for (int i = 0; i < 4; i++)
            af[i] = *(const short8*)(&a_lds[(wm + i * 16 + lr) * 32 + lk]);
#pragma unroll
        for (int j = 0; j < 4; j++)
            bfr[j] = *(const short8*)(&b_lds[(wn + j * 16 + lr) * 32 + lk]);
#pragma unroll
        for (int i = 0; i < 4; i++)
#pragma unroll
            for (int j = 0; j < 4; j++)
                acc[i][j] = MFMA16(af[i], bfr[j], acc[i][j]);
        __syncthreads();
    }
#pragma unroll
    for (int i = 0; i < 4; i++)
#pragma unroll
        for (int j = 0; j < 4; j++)
#pragma unroll
            for (int r = 0; r < 4; r++) {
                int row = m0 + wm + i * 16 + quad * 4 + r;
                int col = n0 + wn + j * 16 + lr;
                if (OUTF32)
                    ((float*)Co)[(size_t)row * ldc + col] = acc[i][j][r];
                else
                    ((unsigned short*)Co)[(size_t)row * ldc + col] = f2bf(acc[i][j][r]);
            }
}

// ---------------------------------------------------------------------------
// attention core: one 16-q-row group vs one 64-key staged tile.
// K LDS swizzle: chunk' = chunk ^ (key&15) (16B granules). V: chunk ^ (d&7).
// P uses padded [72] rows (2-way = free).
// ---------------------------------------------------------------------------
__device__ __forceinline__ void attn_core(const short8 (&qf)[4], floatx4 (&o_acc)[8],
                                          float (&m_i)[4], float (&l_i)[4],
                                          const unsigned short* kb_lds,
                                          const unsigned short* vb_lds,
                                          unsigned short* p_w,
                                          int qrow0, int tk0, int lr, int quad, int lk) {
    floatx4 zero4 = {0.f, 0.f, 0.f, 0.f};
    const float scale = 0.08838834764831845f;

    floatx4 s[4];
#pragma unroll
    for (int n = 0; n < 4; n++) {
        s[n] = zero4;
#pragma unroll
        for (int c = 0; c < 4; c++) {
            short8 kb = *(const short8*)(
                &kb_lds[(n * 16 + lr) * 128 + (((c * 4 + quad) ^ lr) * 8)]);
            s[n] = MFMA16(qf[c], kb, s[n]);
        }
    }

    float rmax[4];
#pragma unroll
    for (int r = 0; r < 4; r++) {
        int tqr = qrow0 + quad * 4 + r;
        float mx = -1e30f;
#pragma unroll
        for (int n = 0; n < 4; n++) {
            int tk = tk0 + n * 16 + lr;
            float sv = s[n][r] * scale;
            sv = (tk > tqr) ? -1e30f : sv;
            s[n][r] = sv;
            mx = fmaxf(mx, sv);
        }
        rmax[r] = mx;
    }
#pragma unroll
    for (int off = 1; off < 16; off <<= 1)
#pragma unroll
        for (int r = 0; r < 4; r++)
            rmax[r] = fmaxf(rmax[r], __shfl_xor(rmax[r], off, 64));

    float alpha[4], rsum[4];
#pragma unroll
    for (int r = 0; r < 4; r++) {
        float mn = fmaxf(m_i[r], rmax[r]);
        alpha[r] = __expf(m_i[r] - mn);
        m_i[r] = mn;
        rsum[r] = 0.f;
    }
#pragma unroll
    for (int n = 0; n < 4; n++)
#pragma unroll
        for (int r = 0; r < 4; r++) {
            float p = __expf(s[n][r] - m_i[r]);
            rsum[r] += p;
            p_w[(quad * 4 + r) * 72 + n * 16 + lr] = f2bf(p);
        }
#pragma unroll
    for (int off = 1; off < 16; off <<= 1)
#pragma unroll
        for (int r = 0; r < 4; r++)
            rsum[r] += __shfl_xor(rsum[r], off, 64);
#pragma unroll
    for (int r = 0; r < 4; r++) l_i[r] = l_i[r] * alpha[r] + rsum[r];

#pragma unroll
    for (int dt = 0; dt < 8; dt++)
#pragma unroll
        for (int r = 0; r < 4; r++) o_acc[dt][r] *= alpha[r];

    short8 pa[2];
#pragma unroll
    for (int kc = 0; kc < 2; kc++)
        pa[kc] = *(const short8*)(&p_w[lr * 72 + kc * 32 + lk]);
#pragma unroll
    for (int dt = 0; dt < 8; dt++) {
#pragma unroll
        for (int kc = 0; kc < 2; kc++) {
            short8 vb = *(const short8*)(
                &vb_lds[(dt * 16 + lr) * 64 + (((kc * 4 + quad) ^ (lr & 7)) * 8)]);
            o_acc[dt] = MFMA16(pa[kc], vb, o_acc[dt]);
        }
    }
}

// -------- flash attention: 128 q-rows/block, 8 waves, 64-key tiles ----------
// T14 async reg-staging with a SINGLE prefetch buffer:
//   lwrite(buf) [waits vmcnt] -> barrier -> gload(kt+1 -> buf) -> compute(kt)
// loads for kt+1 fly under compute(kt); lwrite consumes regs before re-issue.
__global__ __launch_bounds__(512, 4) void attn_fast(unsigned short* qkv,
                                                    const unsigned short* __restrict__ VT) {
    const int T = 2048, Cc = 2048, Dd = 128;
    int qt = 15 - (int)blockIdx.x;                // heavy tiles dispatch first
    int bh = blockIdx.y;
    int b = bh >> 4, h = bh & 15;
    int tid = threadIdx.x, lane = tid & 63, w = tid >> 6;   // w in [0,8)
    int lr = lane & 15, quad = lane >> 4, lk = quad * 8;
    int t0 = qt * 128;

    __shared__ __align__(16) unsigned short k_lds[64 * 128];   // [key][d] swz
    __shared__ __align__(16) unsigned short v_lds[128 * 64];   // [d][key] swz
    __shared__ __align__(16) unsigned short p_lds[8][16][72];  // per-wave P

    short8 qf[4];
    {
        size_t qrow = (size_t)(b * T + t0 + w * 16 + lr) * 3 * Cc + h * Dd;
#pragma unroll
        for (int c = 0; c < 4; c++)
            qf[c] = *(const short8*)(&qkv[qrow + c * 32 + lk]);
    }

    floatx4 o_acc[8];
    floatx4 zero4 = {0.f, 0.f, 0.f, 0.f};
#pragma unroll
    for (int i = 0; i < 8; i++) o_acc[i] = zero4;
    float m_i[4], l_i[4];
#pragma unroll
    for (int r = 0; r < 4; r++) { m_i[r] = -1e30f; l_i[r] = 0.f; }

    // staging geometry (per thread: 2 K chunks + 2 V chunks of 16B)
    int krow[2], kslot[2], vrow[2], vslot[2];
#pragma unroll
    for (int i = 0; i < 2; i++) {
        int c = i * 512 + tid;
        krow[i] = c >> 4; kslot[i] = c & 15;       // K: 64 rows x 16 chunks
        vrow[i] = c >> 3; vslot[i] = c & 7;        // V: 128 rows x 8 chunks
    }
    uint4v kA[2], vA[2];
    auto gload = [&](int kt) {
        int tk0 = kt * 64;
#pragma unroll
        for (int i = 0; i < 2; i++) {
            kA[i] = *(const uint4v*)(
                &qkv[((size_t)(b * T + tk0 + krow[i]) * 3 + 1) * Cc + h * Dd + kslot[i] * 8]);
            vA[i] = *(const uint4v*)(
                &VT[((size_t)bh * Dd + vrow[i]) * T + tk0 + vslot[i] * 8]);
        }
    };
    auto lwrite = [&]() {
#pragma unroll
        for (int i = 0; i < 2; i++) {
            *(uint4v*)(&k_lds[krow[i] * 128 + ((kslot[i] ^ (krow[i] & 15)) * 8)]) = kA[i];
            *(uint4v*)(&v_lds[vrow[i] * 64 + ((vslot[i] ^ (vrow[i] & 7)) * 8)]) = vA[i];
        }
    };

    int nkt = 2 * qt + 2;
    gload(0);

    for (int kt = 0; kt < nkt; kt++) {
        lwrite();                                  // waits on in-flight loads
        __syncthreads();                           // LDS tile ready
        if (kt + 1 < nkt) gload(kt + 1);           // flies under compute(kt)
        int tk0 = kt * 64;
        if (tk0 <= t0 + w * 16 + 15)               // wave-uniform skip
            attn_core(qf, o_acc, m_i, l_i, k_lds, v_lds, &p_lds[w][0][0],
                      t0 + w * 16, tk0, lr, quad, lk);
        __syncthreads();                           // all reads of tile kt done
    }

    // epilogue: O over q slots -> qkv[b, t, 0, h, d]
#pragma unroll
    for (int dt = 0; dt < 8; dt++)
#pragma unroll
        for (int r = 0; r < 4; r++) {
            int row = t0 + w * 16 + quad * 4 + r;
            int col = dt * 16 + lr;
            qkv[(size_t)(b * T + row) * 3 * Cc + h * Dd + col] = f2bf(o_acc[dt][r] * (1.0f / l_i[r]));
        }
}

// ---------------------------------------------------------------------------
extern "C" void kernel_launch(void* const* d_in, const int* in_sizes, int n_in,
                              void* d_out, int out_size, void* d_ws, size_t ws_size,
                              hipStream_t stream) {
    const float* x    = (const float*)d_in[0];
    const float* wqkv = (const float*)d_in[1];
    const float* wout = (const float*)d_in[2];
    const float* cosT = (const float*)d_in[3];
    const float* sinT = (const float*)d_in[4];
    float* out = (float*)d_out;

    unsigned short* qkv = (unsigned short*)d_ws;          // 48 MiB
    const size_t QKV = 25165824, XBF = 8388608;
    unsigned short* xbf = qkv + QKV;                      // 16 MiB; VT overlays after gemm1
    unsigned short* wTq = xbf + XBF;                      // 24 MiB; wTo overlays after gemm1
    unsigned short* VT  = xbf;
    unsigned short* wTo = wTq;

    cvt_k<<<4096, 256, 0, stream>>>(x, xbf, 8388608);
    transpose_f2b_k<<<dim3(192, 64), 256, 0, stream>>>(wqkv, wTq, 2048, 6144);
    gemm_bt<false><<<dim3(48, 32), 256, 0, stream>>>(xbf, 2048, wTq, qkv, 6144,
                                                     4096, 6144, 2048);
    rotary_k<<<32768, 256, 0, stream>>>(qkv, cosT, sinT);
    transpose_f2b_k<<<dim3(64, 64), 256, 0, stream>>>(wout, wTo, 2048, 2048);
    transpose_v_k<<<dim3(64, 4, 32), 256, 0, stream>>>(qkv, VT);
    attn_fast<<<dim3(16, 32), 512, 0, stream>>>(qkv, VT);
    gemm_bt<true><<<dim3(16, 32), 256, 0, stream>>>(qkv, 6144, wTo, out, 2048,
                                                    4096, 2048, 2048);
}

// Round 5
// 501.771 us; speedup vs baseline: 1.2915x; 1.0021x over previous
//
#include <hip/hip_runtime.h>

// ---------------------------------------------------------------------------
// MultiHeadAttention: B=2, T=2048, C=2048, H=16, D=128. fp32 in, fp32 out.
// Internals: bf16 MFMA, fp32 accum. ws >= 92.3MB confirmed in round 6.
// R7: GEMMs use global_load_lds (m97); attention 128-q-tile, 8 waves/block.
// R8/R9: paired-tile + global_load_lds dbuf -> 7x HBM traffic. REVERTED.
// R10/R11: T14 reg-staging + XOR-swizzled K/V LDS. Conflicts 9.2M->0.54M but
//          time neutral: (a) CU imbalance (adjacent-qt pairs, 62 vs 34 units),
//          (b) __syncthreads drains vmcnt(0), killing the prefetch at bar2.
// R12: balanced qt interleave (consecutive blocks sum ~const) + raw s_barrier
//      with lgkmcnt(0)-only waits so the global prefetch stays in flight
//      across both barriers (vmcnt counted by register dependence at lwrite).
// ---------------------------------------------------------------------------

typedef __attribute__((ext_vector_type(8))) short short8;
typedef __attribute__((ext_vector_type(4))) float floatx4;
typedef __attribute__((ext_vector_type(4))) unsigned int uint4v;

#define MFMA16(a, b, c) __builtin_amdgcn_mfma_f32_16x16x32_bf16(a, b, c, 0, 0, 0)

__device__ inline unsigned short f2bf(float f) {
    union { float f; unsigned int i; } v; v.f = f;
    unsigned int r = v.i + 0x7fff + ((v.i >> 16) & 1);   // round-nearest-even
    return (unsigned short)(r >> 16);
}

// async 16B global->LDS (m97). Per-lane lds ptrs must be base + lane*16.
__device__ inline void gl2lds16(const unsigned short* g, unsigned short* l) {
    __builtin_amdgcn_global_load_lds(
        (const __attribute__((address_space(1))) unsigned int*)g,
        (__attribute__((address_space(3))) unsigned int*)l, 16, 0, 0);
}

// workgroup barrier that does NOT drain vmcnt: LDS ordering only.
// rule #18: sched_barrier(0) fences around the inline-asm waitcnt.
__device__ __forceinline__ void bar_lds_only() {
    asm volatile("s_waitcnt lgkmcnt(0)" ::: "memory");
    __builtin_amdgcn_sched_barrier(0);
    __builtin_amdgcn_s_barrier();
    __builtin_amdgcn_sched_barrier(0);
}

// ---------------- fp32 -> bf16 bulk convert (8 elems/thread) -----------------
__global__ __launch_bounds__(256) void cvt_k(const float* __restrict__ in,
                                             unsigned short* __restrict__ out, int n) {
    int i = (blockIdx.x * 256 + threadIdx.x) * 8;
    if (i + 7 < n) {
        float4 v0 = *(const float4*)(&in[i]);
        float4 v1 = *(const float4*)(&in[i + 4]);
        ushort4 o0, o1;
        o0.x = f2bf(v0.x); o0.y = f2bf(v0.y); o0.z = f2bf(v0.z); o0.w = f2bf(v0.w);
        o1.x = f2bf(v1.x); o1.y = f2bf(v1.y); o1.z = f2bf(v1.z); o1.w = f2bf(v1.w);
        *(ushort4*)(&out[i])     = o0;
        *(ushort4*)(&out[i + 4]) = o1;
    } else {
        for (int j = i; j < n; j++) out[j] = f2bf(in[j]);
    }
}

// ---------- fused fp32 transpose+cvt: in[R][Cc] f32 -> out[Cc][R] bf16 -------
__global__ __launch_bounds__(256) void transpose_f2b_k(const float* __restrict__ in,
                                                       unsigned short* __restrict__ out,
                                                       int R, int Cc) {
    __shared__ unsigned short tile[32][33];
    int ct = blockIdx.x * 32;
    int rt = blockIdx.y * 32;
    int tx = threadIdx.x & 31;
    int ty = threadIdx.x >> 5;
#pragma unroll
    for (int i = 0; i < 32; i += 8)
        tile[ty + i][tx] = f2bf(in[(size_t)(rt + ty + i) * Cc + ct + tx]);
    __syncthreads();
#pragma unroll
    for (int i = 0; i < 32; i += 8)
        out[(size_t)(ct + ty + i) * R + rt + tx] = tile[tx][ty + i];
}

// ------------- per-head V transpose: qkv[b,t,2,h,:] -> VT[bh][d][t] ----------
__global__ __launch_bounds__(256) void transpose_v_k(const unsigned short* __restrict__ qkv,
                                                     unsigned short* __restrict__ VT) {
    __shared__ unsigned short tile[32][33];
    int t0 = blockIdx.x * 32;
    int d0 = blockIdx.y * 32;
    int bh = blockIdx.z;
    int b = bh >> 4, h = bh & 15;
    int tx = threadIdx.x & 31;
    int ty = threadIdx.x >> 5;
#pragma unroll
    for (int i = 0; i < 32; i += 8)
        tile[ty + i][tx] =
            qkv[((size_t)(b * 2048 + t0 + ty + i) * 3 + 2) * 2048 + h * 128 + d0 + tx];
    __syncthreads();
#pragma unroll
    for (int i = 0; i < 32; i += 8)
        VT[((size_t)bh * 128 + d0 + ty + i) * 2048 + t0 + tx] = tile[tx][ty + i];
}

// ---------------- RoPE in place on q/k parts of qkv (fp32 cos/sin) -----------
__global__ __launch_bounds__(256) void rotary_k(unsigned short* qkv,
                                                const float* __restrict__ cosT,
                                                const float* __restrict__ sinT) {
    int idx = blockIdx.x * 256 + threadIdx.x;
    int d    = idx & 63;
    int h    = (idx >> 6) & 15;
    int part = (idx >> 10) & 1;
    int t    = (idx >> 11) & 2047;
    int b    = idx >> 22;
    size_t base = ((size_t)(b * 2048 + t) * 3 + part) * 2048 + h * 128;
    float c = cosT[t * 64 + d];
    float s = sinT[t * 64 + d];
    union { unsigned int i; float f; } u1, u2;
    u1.i = ((unsigned int)qkv[base + d]) << 16;
    u2.i = ((unsigned int)qkv[base + d + 64]) << 16;
    float x1 = u1.f, x2 = u2.f;
    qkv[base + d]      = f2bf(x1 * c - x2 * s);
    qkv[base + d + 64] = f2bf(x2 * c + x1 * s);
}

// ---- GEMM (m97): C[M,N] = A[M,K](bf16) * Bt[N,K]^T(bf16), async staging ----
template <bool OUTF32>
__global__ __launch_bounds__(256) void gemm_bt(const unsigned short* __restrict__ A, long lda,
                                               const unsigned short* __restrict__ Bt,
                                               void* __restrict__ Co, long ldc,
                                               int M, int N, int K) {
    __shared__ unsigned short a_lds[128 * 32];   // unpadded: lane-contiguous for DMA
    __shared__ unsigned short b_lds[128 * 32];
    int m0 = blockIdx.y * 128, n0 = blockIdx.x * 128;
    int tid = threadIdx.x;
    int lane = tid & 63, w = tid >> 6;
    int wm = (w >> 1) * 64, wn = (w & 1) * 64;
    int lr = lane & 15, quad = lane >> 4, lk = quad * 8;

    floatx4 acc[4][4];
    floatx4 zero4 = {0.f, 0.f, 0.f, 0.f};
#pragma unroll
    for (int i = 0; i < 4; i++)
#pragma unroll
        for (int j = 0; j < 4; j++) acc[i][j] = zero4;

    for (int k0 = 0; k0 < K; k0 += 32) {
        // 16B chunks: c in [0,512); row = c>>2, seg = c&3. Lane-contiguous LDS.
#pragma unroll
        for (int i = 0; i < 2; i++) {
            int c = w * 128 + i * 64 + lane;
            int row = c >> 2, seg = (c & 3) * 8;
            gl2lds16(&A[(size_t)(m0 + row) * lda + k0 + seg], &a_lds[c * 8]);
            gl2lds16(&Bt[(size_t)(n0 + row) * K + k0 + seg], &b_lds[c * 8]);
        }
        __syncthreads();
        short8 af[4], bfr[4];
#pragma unroll
        for (int i = 0; i < 4; i++)
            af[i] = *(const short8*)(&a_lds[(wm + i * 16 + lr) * 32 + lk]);
#pragma unroll
        for (int j = 0; j < 4; j++)
            bfr[j] = *(const short8*)(&b_lds[(wn + j * 16 + lr) * 32 + lk]);
#pragma unroll
        for (int i = 0; i < 4; i++)
#pragma unroll
            for (int j = 0; j < 4; j++)
                acc[i][j] = MFMA16(af[i], bfr[j], acc[i][j]);
        __syncthreads();
    }
#pragma unroll
    for (int i = 0; i < 4; i++)
#pragma unroll
        for (int j = 0; j < 4; j++)
#pragma unroll
            for (int r = 0; r < 4; r++) {
                int row = m0 + wm + i * 16 + quad * 4 + r;
                int col = n0 + wn + j * 16 + lr;
                if (OUTF32)
                    ((float*)Co)[(size_t)row * ldc + col] = acc[i][j][r];
                else
                    ((unsigned short*)Co)[(size_t)row * ldc + col] = f2bf(acc[i][j][r]);
            }
}

// ---------------------------------------------------------------------------
// attention core: one 16-q-row group vs one 64-key staged tile.
// K LDS swizzle: chunk' = chunk ^ (key&15) (16B granules). V: chunk ^ (d&7).
// P uses padded [72] rows (2-way = free).
// ---------------------------------------------------------------------------
__device__ __forceinline__ void attn_core(const short8 (&qf)[4], floatx4 (&o_acc)[8],
                                          float (&m_i)[4], float (&l_i)[4],
                                          const unsigned short* kb_lds,
                                          const unsigned short* vb_lds,
                                          unsigned short* p_w,
                                          int qrow0, int tk0, int lr, int quad, int lk) {
    floatx4 zero4 = {0.f, 0.f, 0.f, 0.f};
    const float scale = 0.08838834764831845f;

    floatx4 s[4];
#pragma unroll
    for (int n = 0; n < 4; n++) {
        s[n] = zero4;
#pragma unroll
        for (int c = 0; c < 4; c++) {
            short8 kb = *(const short8*)(
                &kb_lds[(n * 16 + lr) * 128 + (((c * 4 + quad) ^ lr) * 8)]);
            s[n] = MFMA16(qf[c], kb, s[n]);
        }
    }

    float rmax[4];
#pragma unroll
    for (int r = 0; r < 4; r++) {
        int tqr = qrow0 + quad * 4 + r;
        float mx = -1e30f;
#pragma unroll
        for (int n = 0; n < 4; n++) {
            int tk = tk0 + n * 16 + lr;
            float sv = s[n][r] * scale;
            sv = (tk > tqr) ? -1e30f : sv;
            s[n][r] = sv;
            mx = fmaxf(mx, sv);
        }
        rmax[r] = mx;
    }
#pragma unroll
    for (int off = 1; off < 16; off <<= 1)
#pragma unroll
        for (int r = 0; r < 4; r++)
            rmax[r] = fmaxf(rmax[r], __shfl_xor(rmax[r], off, 64));

    float alpha[4], rsum[4];
#pragma unroll
    for (int r = 0; r < 4; r++) {
        float mn = fmaxf(m_i[r], rmax[r]);
        alpha[r] = __expf(m_i[r] - mn);
        m_i[r] = mn;
        rsum[r] = 0.f;
    }
#pragma unroll
    for (int n = 0; n < 4; n++)
#pragma unroll
        for (int r = 0; r < 4; r++) {
            float p = __expf(s[n][r] - m_i[r]);
            rsum[r] += p;
            p_w[(quad * 4 + r) * 72 + n * 16 + lr] = f2bf(p);
        }
#pragma unroll
    for (int off = 1; off < 16; off <<= 1)
#pragma unroll
        for (int r = 0; r < 4; r++)
            rsum[r] += __shfl_xor(rsum[r], off, 64);
#pragma unroll
    for (int r = 0; r < 4; r++) l_i[r] = l_i[r] * alpha[r] + rsum[r];

#pragma unroll
    for (int dt = 0; dt < 8; dt++)
#pragma unroll
        for (int r = 0; r < 4; r++) o_acc[dt][r] *= alpha[r];

    short8 pa[2];
#pragma unroll
    for (int kc = 0; kc < 2; kc++)
        pa[kc] = *(const short8*)(&p_w[lr * 72 + kc * 32 + lk]);
#pragma unroll
    for (int dt = 0; dt < 8; dt++) {
#pragma unroll
        for (int kc = 0; kc < 2; kc++) {
            short8 vb = *(const short8*)(
                &vb_lds[(dt * 16 + lr) * 64 + (((kc * 4 + quad) ^ (lr & 7)) * 8)]);
            o_acc[dt] = MFMA16(pa[kc], vb, o_acc[dt]);
        }
    }
}

// -------- flash attention: 128 q-rows/block, 8 waves, 64-key tiles ----------
// T14 async reg-staging, single prefetch buffer. Barriers are lgkmcnt-only
// (LDS ordering) so the global prefetch for kt+1 stays in flight across the
// whole tile; its vmcnt is waited by register dependence at the next lwrite.
__global__ __launch_bounds__(512, 4) void attn_fast(unsigned short* qkv,
                                                    const unsigned short* __restrict__ VT) {
    const int T = 2048, Cc = 2048, Dd = 128;
    // balanced map: x=0..15 -> qt 15,0,14,1,13,2,... so any two consecutive
    // blocks (one CU's pair) total ~34 tile-units instead of 62..6.
    int xx = blockIdx.x;
    int qt = (xx & 1) ? (xx >> 1) : (15 - (xx >> 1));
    int bh = blockIdx.y;
    int b = bh >> 4, h = bh & 15;
    int tid = threadIdx.x, lane = tid & 63, w = tid >> 6;   // w in [0,8)
    int lr = lane & 15, quad = lane >> 4, lk = quad * 8;
    int t0 = qt * 128;

    __shared__ __align__(16) unsigned short k_lds[64 * 128];   // [key][d] swz
    __shared__ __align__(16) unsigned short v_lds[128 * 64];   // [d][key] swz
    __shared__ __align__(16) unsigned short p_lds[8][16][72];  // per-wave P

    short8 qf[4];
    {
        size_t qrow = (size_t)(b * T + t0 + w * 16 + lr) * 3 * Cc + h * Dd;
#pragma unroll
        for (int c = 0; c < 4; c++)
            qf[c] = *(const short8*)(&qkv[qrow + c * 32 + lk]);
    }

    floatx4 o_acc[8];
    floatx4 zero4 = {0.f, 0.f, 0.f, 0.f};
#pragma unroll
    for (int i = 0; i < 8; i++) o_acc[i] = zero4;
    float m_i[4], l_i[4];
#pragma unroll
    for (int r = 0; r < 4; r++) { m_i[r] = -1e30f; l_i[r] = 0.f; }

    // staging geometry (per thread: 2 K chunks + 2 V chunks of 16B)
    int krow[2], kslot[2], vrow[2], vslot[2];
#pragma unroll
    for (int i = 0; i < 2; i++) {
        int c = i * 512 + tid;
        krow[i] = c >> 4; kslot[i] = c & 15;       // K: 64 rows x 16 chunks
        vrow[i] = c >> 3; vslot[i] = c & 7;        // V: 128 rows x 8 chunks
    }
    uint4v kA[2], vA[2];
    auto gload = [&](int kt) {
        int tk0 = kt * 64;
#pragma unroll
        for (int i = 0; i < 2; i++) {
            kA[i] = *(const uint4v*)(
                &qkv[((size_t)(b * T + tk0 + krow[i]) * 3 + 1) * Cc + h * Dd + kslot[i] * 8]);
            vA[i] = *(const uint4v*)(
                &VT[((size_t)bh * Dd + vrow[i]) * T + tk0 + vslot[i] * 8]);
        }
    };
    auto lwrite = [&]() {
#pragma unroll
        for (int i = 0; i < 2; i++) {
            *(uint4v*)(&k_lds[krow[i] * 128 + ((kslot[i] ^ (krow[i] & 15)) * 8)]) = kA[i];
            *(uint4v*)(&v_lds[vrow[i] * 64 + ((vslot[i] ^ (vrow[i] & 7)) * 8)]) = vA[i];
        }
    };

    int nkt = 2 * qt + 2;
    gload(0);

    for (int kt = 0; kt < nkt; kt++) {
        lwrite();                                  // vmcnt waited by dependence
        bar_lds_only();                            // LDS tile ready (no vm drain)
        if (kt + 1 < nkt) gload(kt + 1);           // in flight across whole tile
        int tk0 = kt * 64;
        if (tk0 <= t0 + w * 16 + 15)               // wave-uniform skip
            attn_core(qf, o_acc, m_i, l_i, k_lds, v_lds, &p_lds[w][0][0],
                      t0 + w * 16, tk0, lr, quad, lk);
        bar_lds_only();                            // all reads of tile kt done
    }

    // epilogue: O over q slots -> qkv[b, t, 0, h, d]
#pragma unroll
    for (int dt = 0; dt < 8; dt++)
#pragma unroll
        for (int r = 0; r < 4; r++) {
            int row = t0 + w * 16 + quad * 4 + r;
            int col = dt * 16 + lr;
            qkv[(size_t)(b * T + row) * 3 * Cc + h * Dd + col] = f2bf(o_acc[dt][r] * (1.0f / l_i[r]));
        }
}

// ---------------------------------------------------------------------------
extern "C" void kernel_launch(void* const* d_in, const int* in_sizes, int n_in,
                              void* d_out, int out_size, void* d_ws, size_t ws_size,
                              hipStream_t stream) {
    const float* x    = (const float*)d_in[0];
    const float* wqkv = (const float*)d_in[1];
    const float* wout = (const float*)d_in[2];
    const float* cosT = (const float*)d_in[3];
    const float* sinT = (const float*)d_in[4];
    float* out = (float*)d_out;

    unsigned short* qkv = (unsigned short*)d_ws;          // 48 MiB
    const size_t QKV = 25165824, XBF = 8388608;
    unsigned short* xbf = qkv + QKV;                      // 16 MiB; VT overlays after gemm1
    unsigned short* wTq = xbf + XBF;                      // 24 MiB; wTo overlays after gemm1
    unsigned short* VT  = xbf;
    unsigned short* wTo = wTq;

    cvt_k<<<4096, 256, 0, stream>>>(x, xbf, 8388608);
    transpose_f2b_k<<<dim3(192, 64), 256, 0, stream>>>(wqkv, wTq, 2048, 6144);
    gemm_bt<false><<<dim3(48, 32), 256, 0, stream>>>(xbf, 2048, wTq, qkv, 6144,
                                                     4096, 6144, 2048);
    rotary_k<<<32768, 256, 0, stream>>>(qkv, cosT, sinT);
    transpose_f2b_k<<<dim3(64, 64), 256, 0, stream>>>(wout, wTo, 2048, 2048);
    transpose_v_k<<<dim3(64, 4, 32), 256, 0, stream>>>(qkv, VT);
    attn_fast<<<dim3(16, 32), 512, 0, stream>>>(qkv, VT);
    gemm_bt<true><<<dim3(16, 32), 256, 0, stream>>>(qkv, 6144, wTo, out, 2048,
                                                    4096, 2048, 2048);
}

// Round 6
// 454.583 us; speedup vs baseline: 1.4255x; 1.1038x over previous
//
#include <hip/hip_runtime.h>

// ---------------------------------------------------------------------------
// MultiHeadAttention: B=2, T=2048, C=2048, H=16, D=128. fp32 in, fp32 out.
// Internals: bf16 MFMA, fp32 accum. ws >= 92.3MB confirmed in round 6.
// R7: GEMMs use global_load_lds (m97); attention 128-q-tile, 8 waves/block.
// R8/R9: paired-tile + global_load_lds dbuf -> 7x HBM traffic. REVERTED.
// R10-R12: attn conflicts 9.2M->0.54M, balanced qt, lgkm-only barriers — all
//          NEUTRAL at ~155us. Diagnosis: attn is LDS-PIPE-bound (8 waves x
//          34 b128 reads + 32 shfl + P roundtrip per tile ~ 5.5k cy/tile).
// R13: (a) GEMMs -> 2-phase double-buffered staging (T3 minimum: STAGE(t+1)
//          issued before compute(t), one barrier/tile; loads fly under MFMA).
//      (b) attn: ones-row appended to V^T so l = P*ones falls out of PV MFMA
//          (kills 16 shfl + 16 VALU per wave-tile on the DS pipe).
// ---------------------------------------------------------------------------

typedef __attribute__((ext_vector_type(8))) short short8;
typedef __attribute__((ext_vector_type(4))) float floatx4;
typedef __attribute__((ext_vector_type(4))) unsigned int uint4v;

#define MFMA16(a, b, c) __builtin_amdgcn_mfma_f32_16x16x32_bf16(a, b, c, 0, 0, 0)

__device__ inline unsigned short f2bf(float f) {
    union { float f; unsigned int i; } v; v.f = f;
    unsigned int r = v.i + 0x7fff + ((v.i >> 16) & 1);   // round-nearest-even
    return (unsigned short)(r >> 16);
}

// async 16B global->LDS (m97). Per-lane lds ptrs must be base + lane*16.
__device__ inline void gl2lds16(const unsigned short* g, unsigned short* l) {
    __builtin_amdgcn_global_load_lds(
        (const __attribute__((address_space(1))) unsigned int*)g,
        (__attribute__((address_space(3))) unsigned int*)l, 16, 0, 0);
}

// workgroup barrier that does NOT drain vmcnt: LDS ordering only.
// rule #18: sched_barrier(0) fences around the inline-asm waitcnt.
__device__ __forceinline__ void bar_lds_only() {
    asm volatile("s_waitcnt lgkmcnt(0)" ::: "memory");
    __builtin_amdgcn_sched_barrier(0);
    __builtin_amdgcn_s_barrier();
    __builtin_amdgcn_sched_barrier(0);
}

// ---------------- fp32 -> bf16 bulk convert (8 elems/thread) -----------------
__global__ __launch_bounds__(256) void cvt_k(const float* __restrict__ in,
                                             unsigned short* __restrict__ out, int n) {
    int i = (blockIdx.x * 256 + threadIdx.x) * 8;
    if (i + 7 < n) {
        float4 v0 = *(const float4*)(&in[i]);
        float4 v1 = *(const float4*)(&in[i + 4]);
        ushort4 o0, o1;
        o0.x = f2bf(v0.x); o0.y = f2bf(v0.y); o0.z = f2bf(v0.z); o0.w = f2bf(v0.w);
        o1.x = f2bf(v1.x); o1.y = f2bf(v1.y); o1.z = f2bf(v1.z); o1.w = f2bf(v1.w);
        *(ushort4*)(&out[i])     = o0;
        *(ushort4*)(&out[i + 4]) = o1;
    } else {
        for (int j = i; j < n; j++) out[j] = f2bf(in[j]);
    }
}

// ---------- fused fp32 transpose+cvt: in[R][Cc] f32 -> out[Cc][R] bf16 -------
__global__ __launch_bounds__(256) void transpose_f2b_k(const float* __restrict__ in,
                                                       unsigned short* __restrict__ out,
                                                       int R, int Cc) {
    __shared__ unsigned short tile[32][33];
    int ct = blockIdx.x * 32;
    int rt = blockIdx.y * 32;
    int tx = threadIdx.x & 31;
    int ty = threadIdx.x >> 5;
#pragma unroll
    for (int i = 0; i < 32; i += 8)
        tile[ty + i][tx] = f2bf(in[(size_t)(rt + ty + i) * Cc + ct + tx]);
    __syncthreads();
#pragma unroll
    for (int i = 0; i < 32; i += 8)
        out[(size_t)(ct + ty + i) * R + rt + tx] = tile[tx][ty + i];
}

// ------------- per-head V transpose: qkv[b,t,2,h,:] -> VT[bh][d][t] ----------
__global__ __launch_bounds__(256) void transpose_v_k(const unsigned short* __restrict__ qkv,
                                                     unsigned short* __restrict__ VT) {
    __shared__ unsigned short tile[32][33];
    int t0 = blockIdx.x * 32;
    int d0 = blockIdx.y * 32;
    int bh = blockIdx.z;
    int b = bh >> 4, h = bh & 15;
    int tx = threadIdx.x & 31;
    int ty = threadIdx.x >> 5;
#pragma unroll
    for (int i = 0; i < 32; i += 8)
        tile[ty + i][tx] =
            qkv[((size_t)(b * 2048 + t0 + ty + i) * 3 + 2) * 2048 + h * 128 + d0 + tx];
    __syncthreads();
#pragma unroll
    for (int i = 0; i < 32; i += 8)
        VT[((size_t)bh * 128 + d0 + ty + i) * 2048 + t0 + tx] = tile[tx][ty + i];
}

// ---------------- RoPE in place on q/k parts of qkv (fp32 cos/sin) -----------
__global__ __launch_bounds__(256) void rotary_k(unsigned short* qkv,
                                                const float* __restrict__ cosT,
                                                const float* __restrict__ sinT) {
    int idx = blockIdx.x * 256 + threadIdx.x;
    int d    = idx & 63;
    int h    = (idx >> 6) & 15;
    int part = (idx >> 10) & 1;
    int t    = (idx >> 11) & 2047;
    int b    = idx >> 22;
    size_t base = ((size_t)(b * 2048 + t) * 3 + part) * 2048 + h * 128;
    float c = cosT[t * 64 + d];
    float s = sinT[t * 64 + d];
    union { unsigned int i; float f; } u1, u2;
    u1.i = ((unsigned int)qkv[base + d]) << 16;
    u2.i = ((unsigned int)qkv[base + d + 64]) << 16;
    float x1 = u1.f, x2 = u2.f;
    qkv[base + d]      = f2bf(x1 * c - x2 * s);
    qkv[base + d + 64] = f2bf(x2 * c + x1 * s);
}

// ---- GEMM: C[M,N] = A[M,K](bf16) * Bt[N,K]^T(bf16) --------------------------
// R13: 2-phase double-buffered global_load_lds staging — loads for K-step t+1
// are issued BEFORE compute(t) and stay in flight under the MFMAs; one
// __syncthreads per K-step (drains vmcnt -> next buffer ready).
template <bool OUTF32>
__global__ __launch_bounds__(256) void gemm_bt(const unsigned short* __restrict__ A, long lda,
                                               const unsigned short* __restrict__ Bt,
                                               void* __restrict__ Co, long ldc,
                                               int M, int N, int K) {
    __shared__ unsigned short a_lds[2][128 * 32];   // unpadded: lane-contiguous DMA
    __shared__ unsigned short b_lds[2][128 * 32];
    int m0 = blockIdx.y * 128, n0 = blockIdx.x * 128;
    int tid = threadIdx.x;
    int lane = tid & 63, w = tid >> 6;
    int wm = (w >> 1) * 64, wn = (w & 1) * 64;
    int lr = lane & 15, quad = lane >> 4, lk = quad * 8;

    floatx4 acc[4][4];
    floatx4 zero4 = {0.f, 0.f, 0.f, 0.f};
#pragma unroll
    for (int i = 0; i < 4; i++)
#pragma unroll
        for (int j = 0; j < 4; j++) acc[i][j] = zero4;

    auto stage = [&](int k0, int buf) {
        // 16B chunks: c in [0,512); row = c>>2, seg = c&3. Lane-contiguous LDS.
#pragma unroll
        for (int i = 0; i < 2; i++) {
            int c = w * 128 + i * 64 + lane;
            int row = c >> 2, seg = (c & 3) * 8;
            gl2lds16(&A[(size_t)(m0 + row) * lda + k0 + seg], &a_lds[buf][c * 8]);
            gl2lds16(&Bt[(size_t)(n0 + row) * K + k0 + seg], &b_lds[buf][c * 8]);
        }
    };

    int nt = K >> 5;
    stage(0, 0);
    __syncthreads();                          // buf0 ready
    for (int t = 0; t < nt; t++) {
        int buf = t & 1;
        if (t + 1 < nt) stage((t + 1) * 32, buf ^ 1);   // flies under MFMA(t)
        short8 af[4], bfr[4];
#pragma unroll
        for (int i = 0; i < 4; i++)
            af[i] = *(const short8*)(&a_lds[buf][(wm + i * 16 + lr) * 32 + lk]);
#pragma unroll
        for (int j = 0; j < 4; j++)
            bfr[j] = *(const short8*)(&b_lds[buf][(wn + j * 16 + lr) * 32 + lk]);
#pragma unroll
        for (int i = 0; i < 4; i++)
#pragma unroll
            for (int j = 0; j < 4; j++)
                acc[i][j] = MFMA16(af[i], bfr[j], acc[i][j]);
        __syncthreads();                      // drains vmcnt -> buf^1 ready;
    }                                         // all reads of buf done
#pragma unroll
    for (int i = 0; i < 4; i++)
#pragma unroll
        for (int j = 0; j < 4; j++)
#pragma unroll
            for (int r = 0; r < 4; r++) {
                int row = m0 + wm + i * 16 + quad * 4 + r;
                int col = n0 + wn + j * 16 + lr;
                if (OUTF32)
                    ((float*)Co)[(size_t)row * ldc + col] = acc[i][j][r];
                else
                    ((unsigned short*)Co)[(size_t)row * ldc + col] = f2bf(acc[i][j][r]);
            }
}

// ---------------------------------------------------------------------------
// attention core: one 16-q-row group vs one 64-key staged tile.
// K LDS swizzle: chunk' = chunk ^ (key&15) (16B granules). V: chunk ^ (d&7).
// P uses padded [72] rows (2-way = free).
// R13: l comes from PV MFMA vs the ones-row (V^T row 128) — no rsum shuffles.
// ---------------------------------------------------------------------------
__device__ __forceinline__ void attn_core(const short8 (&qf)[4], floatx4 (&o_acc)[8],
                                          floatx4& o_l,
                                          float (&m_i)[4],
                                          const unsigned short* kb_lds,
                                          const unsigned short* vb_lds,
                                          unsigned short* p_w,
                                          int qrow0, int tk0, int lr, int quad, int lk) {
    floatx4 zero4 = {0.f, 0.f, 0.f, 0.f};
    const float scale = 0.08838834764831845f;

    floatx4 s[4];
#pragma unroll
    for (int n = 0; n < 4; n++) {
        s[n] = zero4;
#pragma unroll
        for (int c = 0; c < 4; c++) {
            short8 kb = *(const short8*)(
                &kb_lds[(n * 16 + lr) * 128 + (((c * 4 + quad) ^ lr) * 8)]);
            s[n] = MFMA16(qf[c], kb, s[n]);
        }
    }

    float rmax[4];
#pragma unroll
    for (int r = 0; r < 4; r++) {
        int tqr = qrow0 + quad * 4 + r;
        float mx = -1e30f;
#pragma unroll
        for (int n = 0; n < 4; n++) {
            int tk = tk0 + n * 16 + lr;
            float sv = s[n][r] * scale;
            sv = (tk > tqr) ? -1e30f : sv;
            s[n][r] = sv;
            mx = fmaxf(mx, sv);
        }
        rmax[r] = mx;
    }
#pragma unroll
    for (int off = 1; off < 16; off <<= 1)
#pragma unroll
        for (int r = 0; r < 4; r++)
            rmax[r] = fmaxf(rmax[r], __shfl_xor(rmax[r], off, 64));

    float alpha[4];
#pragma unroll
    for (int r = 0; r < 4; r++) {
        float mn = fmaxf(m_i[r], rmax[r]);
        alpha[r] = __expf(m_i[r] - mn);
        m_i[r] = mn;
    }
#pragma unroll
    for (int n = 0; n < 4; n++)
#pragma unroll
        for (int r = 0; r < 4; r++) {
            float p = __expf(s[n][r] - m_i[r]);
            p_w[(quad * 4 + r) * 72 + n * 16 + lr] = f2bf(p);
        }

#pragma unroll
    for (int dt = 0; dt < 8; dt++)
#pragma unroll
        for (int r = 0; r < 4; r++) o_acc[dt][r] *= alpha[r];
#pragma unroll
    for (int r = 0; r < 4; r++) o_l[r] *= alpha[r];

    short8 pa[2];
#pragma unroll
    for (int kc = 0; kc < 2; kc++)
        pa[kc] = *(const short8*)(&p_w[lr * 72 + kc * 32 + lk]);
#pragma unroll
    for (int dt = 0; dt < 8; dt++) {
#pragma unroll
        for (int kc = 0; kc < 2; kc++) {
            short8 vb = *(const short8*)(
                &vb_lds[(dt * 16 + lr) * 64 + (((kc * 4 + quad) ^ (lr & 7)) * 8)]);
            o_acc[dt] = MFMA16(pa[kc], vb, o_acc[dt]);
        }
    }
    // l = P x ones via the ones-row (row 128, unswizzled; broadcast over lr)
#pragma unroll
    for (int kc = 0; kc < 2; kc++) {
        short8 vb1 = *(const short8*)(&vb_lds[128 * 64 + (kc * 4 + quad) * 8]);
        o_l = MFMA16(pa[kc], vb1, o_l);
    }
}

// -------- flash attention: 128 q-rows/block, 8 waves, 64-key tiles ----------
// T14 async reg-staging, single prefetch buffer. Barriers are lgkmcnt-only
// (LDS ordering) so the global prefetch for kt+1 stays in flight across the
// whole tile; its vmcnt is waited by register dependence at the next lwrite.
__global__ __launch_bounds__(512, 4) void attn_fast(unsigned short* qkv,
                                                    const unsigned short* __restrict__ VT) {
    const int T = 2048, Cc = 2048, Dd = 128;
    // balanced map: x=0..15 -> qt 15,0,14,1,13,2,... so any two consecutive
    // blocks (one CU's pair) total ~34 tile-units instead of 62..6.
    int xx = blockIdx.x;
    int qt = (xx & 1) ? (xx >> 1) : (15 - (xx >> 1));
    int bh = blockIdx.y;
    int b = bh >> 4, h = bh & 15;
    int tid = threadIdx.x, lane = tid & 63, w = tid >> 6;   // w in [0,8)
    int lr = lane & 15, quad = lane >> 4, lk = quad * 8;
    int t0 = qt * 128;

    __shared__ __align__(16) unsigned short k_lds[64 * 128];    // [key][d] swz
    __shared__ __align__(16) unsigned short v_lds[129 * 64];    // [d][key] swz + ones row
    __shared__ __align__(16) unsigned short p_lds[8][16][72];   // per-wave P

    if (tid < 64) v_lds[128 * 64 + tid] = 0x3F80;   // bf16 1.0 ones-row (static)

    short8 qf[4];
    {
        size_t qrow = (size_t)(b * T + t0 + w * 16 + lr) * 3 * Cc + h * Dd;
#pragma unroll
        for (int c = 0; c < 4; c++)
            qf[c] = *(const short8*)(&qkv[qrow + c * 32 + lk]);
    }

    floatx4 o_acc[8];
    floatx4 zero4 = {0.f, 0.f, 0.f, 0.f};
#pragma unroll
    for (int i = 0; i < 8; i++) o_acc[i] = zero4;
    floatx4 o_l = zero4;
    float m_i[4];
#pragma unroll
    for (int r = 0; r < 4; r++) m_i[r] = -1e30f;

    // staging geometry (per thread: 2 K chunks + 2 V chunks of 16B)
    int krow[2], kslot[2], vrow[2], vslot[2];
#pragma unroll
    for (int i = 0; i < 2; i++) {
        int c = i * 512 + tid;
        krow[i] = c >> 4; kslot[i] = c & 15;       // K: 64 rows x 16 chunks
        vrow[i] = c >> 3; vslot[i] = c & 7;        // V: 128 rows x 8 chunks
    }
    uint4v kA[2], vA[2];
    auto gload = [&](int kt) {
        int tk0 = kt * 64;
#pragma unroll
        for (int i = 0; i < 2; i++) {
            kA[i] = *(const uint4v*)(
                &qkv[((size_t)(b * T + tk0 + krow[i]) * 3 + 1) * Cc + h * Dd + kslot[i] * 8]);
            vA[i] = *(const uint4v*)(
                &VT[((size_t)bh * Dd + vrow[i]) * T + tk0 + vslot[i] * 8]);
        }
    };
    auto lwrite = [&]() {
#pragma unroll
        for (int i = 0; i < 2; i++) {
            *(uint4v*)(&k_lds[krow[i] * 128 + ((kslot[i] ^ (krow[i] & 15)) * 8)]) = kA[i];
            *(uint4v*)(&v_lds[vrow[i] * 64 + ((vslot[i] ^ (vrow[i] & 7)) * 8)]) = vA[i];
        }
    };

    int nkt = 2 * qt + 2;
    gload(0);

    for (int kt = 0; kt < nkt; kt++) {
        lwrite();                                  // vmcnt waited by dependence
        bar_lds_only();                            // LDS tile ready (no vm drain)
        if (kt + 1 < nkt) gload(kt + 1);           // in flight across whole tile
        int tk0 = kt * 64;
        if (tk0 <= t0 + w * 16 + 15)               // wave-uniform skip
            attn_core(qf, o_acc, o_l, m_i, k_lds, v_lds, &p_lds[w][0][0],
                      t0 + w * 16, tk0, lr, quad, lk);
        bar_lds_only();                            // all reads of tile kt done
    }

    // epilogue: O over q slots -> qkv[b, t, 0, h, d]
#pragma unroll
    for (int dt = 0; dt < 8; dt++)
#pragma unroll
        for (int r = 0; r < 4; r++) {
            int row = t0 + w * 16 + quad * 4 + r;
            int col = dt * 16 + lr;
            qkv[(size_t)(b * T + row) * 3 * Cc + h * Dd + col] = f2bf(o_acc[dt][r] * (1.0f / o_l[r]));
        }
}

// ---------------------------------------------------------------------------
extern "C" void kernel_launch(void* const* d_in, const int* in_sizes, int n_in,
                              void* d_out, int out_size, void* d_ws, size_t ws_size,
                              hipStream_t stream) {
    const float* x    = (const float*)d_in[0];
    const float* wqkv = (const float*)d_in[1];
    const float* wout = (const float*)d_in[2];
    const float* cosT = (const float*)d_in[3];
    const float* sinT = (const float*)d_in[4];
    float* out = (float*)d_out;

    unsigned short* qkv = (unsigned short*)d_ws;          // 48 MiB
    const size_t QKV = 25165824, XBF = 8388608;
    unsigned short* xbf = qkv + QKV;                      // 16 MiB; VT overlays after gemm1
    unsigned short* wTq = xbf + XBF;                      // 24 MiB; wTo overlays after gemm1
    unsigned short* VT  = xbf;
    unsigned short* wTo = wTq;

    cvt_k<<<4096, 256, 0, stream>>>(x, xbf, 8388608);
    transpose_f2b_k<<<dim3(192, 64), 256, 0, stream>>>(wqkv, wTq, 2048, 6144);
    gemm_bt<false><<<dim3(48, 32), 256, 0, stream>>>(xbf, 2048, wTq, qkv, 6144,
                                                     4096, 6144, 2048);
    rotary_k<<<32768, 256, 0, stream>>>(qkv, cosT, sinT);
    transpose_f2b_k<<<dim3(64, 64), 256, 0, stream>>>(wout, wTo, 2048, 2048);
    transpose_v_k<<<dim3(64, 4, 32), 256, 0, stream>>>(qkv, VT);
    attn_fast<<<dim3(16, 32), 512, 0, stream>>>(qkv, VT);
    gemm_bt<true><<<dim3(16, 32), 256, 0, stream>>>(qkv, 6144, wTo, out, 2048,
                                                    4096, 2048, 2048);
}

// Round 7
// 448.752 us; speedup vs baseline: 1.4440x; 1.0130x over previous
//
#include <hip/hip_runtime.h>

// ---------------------------------------------------------------------------
// MultiHeadAttention: B=2, T=2048, C=2048, H=16, D=128. fp32 in, fp32 out.
// Internals: bf16 MFMA, fp32 accum.
// R13: GEMMs 2-phase dbuf; attn ones-row PV for l. 454.6us (attn 136).
// R14: attn -> 4 waves x 32 q-rows (two 16-row groups/wave), B-operand reg
//      reuse: each kb/vb LDS read feeds 2 MFMAs. Halves DS reads per q-row,
//      halves barriers per unit compute, doubles intra-wave ILP.
// ---------------------------------------------------------------------------

typedef __attribute__((ext_vector_type(8))) short short8;
typedef __attribute__((ext_vector_type(4))) float floatx4;
typedef __attribute__((ext_vector_type(4))) unsigned int uint4v;

#define MFMA16(a, b, c) __builtin_amdgcn_mfma_f32_16x16x32_bf16(a, b, c, 0, 0, 0)

__device__ inline unsigned short f2bf(float f) {
    union { float f; unsigned int i; } v; v.f = f;
    unsigned int r = v.i + 0x7fff + ((v.i >> 16) & 1);   // round-nearest-even
    return (unsigned short)(r >> 16);
}

// async 16B global->LDS (m97). Per-lane lds ptrs must be base + lane*16.
__device__ inline void gl2lds16(const unsigned short* g, unsigned short* l) {
    __builtin_amdgcn_global_load_lds(
        (const __attribute__((address_space(1))) unsigned int*)g,
        (__attribute__((address_space(3))) unsigned int*)l, 16, 0, 0);
}

// workgroup barrier that does NOT drain vmcnt: LDS ordering only.
__device__ __forceinline__ void bar_lds_only() {
    asm volatile("s_waitcnt lgkmcnt(0)" ::: "memory");
    __builtin_amdgcn_sched_barrier(0);
    __builtin_amdgcn_s_barrier();
    __builtin_amdgcn_sched_barrier(0);
}

// ---------------- fp32 -> bf16 bulk convert (8 elems/thread) -----------------
__global__ __launch_bounds__(256) void cvt_k(const float* __restrict__ in,
                                             unsigned short* __restrict__ out, int n) {
    int i = (blockIdx.x * 256 + threadIdx.x) * 8;
    if (i + 7 < n) {
        float4 v0 = *(const float4*)(&in[i]);
        float4 v1 = *(const float4*)(&in[i + 4]);
        ushort4 o0, o1;
        o0.x = f2bf(v0.x); o0.y = f2bf(v0.y); o0.z = f2bf(v0.z); o0.w = f2bf(v0.w);
        o1.x = f2bf(v1.x); o1.y = f2bf(v1.y); o1.z = f2bf(v1.z); o1.w = f2bf(v1.w);
        *(ushort4*)(&out[i])     = o0;
        *(ushort4*)(&out[i + 4]) = o1;
    } else {
        for (int j = i; j < n; j++) out[j] = f2bf(in[j]);
    }
}

// ---------- fused fp32 transpose+cvt: in[R][Cc] f32 -> out[Cc][R] bf16 -------
__global__ __launch_bounds__(256) void transpose_f2b_k(const float* __restrict__ in,
                                                       unsigned short* __restrict__ out,
                                                       int R, int Cc) {
    __shared__ unsigned short tile[32][33];
    int ct = blockIdx.x * 32;
    int rt = blockIdx.y * 32;
    int tx = threadIdx.x & 31;
    int ty = threadIdx.x >> 5;
#pragma unroll
    for (int i = 0; i < 32; i += 8)
        tile[ty + i][tx] = f2bf(in[(size_t)(rt + ty + i) * Cc + ct + tx]);
    __syncthreads();
#pragma unroll
    for (int i = 0; i < 32; i += 8)
        out[(size_t)(ct + ty + i) * R + rt + tx] = tile[tx][ty + i];
}

// ------------- per-head V transpose: qkv[b,t,2,h,:] -> VT[bh][d][t] ----------
__global__ __launch_bounds__(256) void transpose_v_k(const unsigned short* __restrict__ qkv,
                                                     unsigned short* __restrict__ VT) {
    __shared__ unsigned short tile[32][33];
    int t0 = blockIdx.x * 32;
    int d0 = blockIdx.y * 32;
    int bh = blockIdx.z;
    int b = bh >> 4, h = bh & 15;
    int tx = threadIdx.x & 31;
    int ty = threadIdx.x >> 5;
#pragma unroll
    for (int i = 0; i < 32; i += 8)
        tile[ty + i][tx] =
            qkv[((size_t)(b * 2048 + t0 + ty + i) * 3 + 2) * 2048 + h * 128 + d0 + tx];
    __syncthreads();
#pragma unroll
    for (int i = 0; i < 32; i += 8)
        VT[((size_t)bh * 128 + d0 + ty + i) * 2048 + t0 + tx] = tile[tx][ty + i];
}

// ---------------- RoPE in place on q/k parts of qkv (fp32 cos/sin) -----------
__global__ __launch_bounds__(256) void rotary_k(unsigned short* qkv,
                                                const float* __restrict__ cosT,
                                                const float* __restrict__ sinT) {
    int idx = blockIdx.x * 256 + threadIdx.x;
    int d    = idx & 63;
    int h    = (idx >> 6) & 15;
    int part = (idx >> 10) & 1;
    int t    = (idx >> 11) & 2047;
    int b    = idx >> 22;
    size_t base = ((size_t)(b * 2048 + t) * 3 + part) * 2048 + h * 128;
    float c = cosT[t * 64 + d];
    float s = sinT[t * 64 + d];
    union { unsigned int i; float f; } u1, u2;
    u1.i = ((unsigned int)qkv[base + d]) << 16;
    u2.i = ((unsigned int)qkv[base + d + 64]) << 16;
    float x1 = u1.f, x2 = u2.f;
    qkv[base + d]      = f2bf(x1 * c - x2 * s);
    qkv[base + d + 64] = f2bf(x2 * c + x1 * s);
}

// ---- GEMM: C[M,N] = A[M,K](bf16) * Bt[N,K]^T(bf16), 2-phase dbuf staging ----
template <bool OUTF32>
__global__ __launch_bounds__(256) void gemm_bt(const unsigned short* __restrict__ A, long lda,
                                               const unsigned short* __restrict__ Bt,
                                               void* __restrict__ Co, long ldc,
                                               int M, int N, int K) {
    __shared__ unsigned short a_lds[2][128 * 32];   // unpadded: lane-contiguous DMA
    __shared__ unsigned short b_lds[2][128 * 32];
    int m0 = blockIdx.y * 128, n0 = blockIdx.x * 128;
    int tid = threadIdx.x;
    int lane = tid & 63, w = tid >> 6;
    int wm = (w >> 1) * 64, wn = (w & 1) * 64;
    int lr = lane & 15, quad = lane >> 4, lk = quad * 8;

    floatx4 acc[4][4];
    floatx4 zero4 = {0.f, 0.f, 0.f, 0.f};
#pragma unroll
    for (int i = 0; i < 4; i++)
#pragma unroll
        for (int j = 0; j < 4; j++) acc[i][j] = zero4;

    auto stage = [&](int k0, int buf) {
#pragma unroll
        for (int i = 0; i < 2; i++) {
            int c = w * 128 + i * 64 + lane;
            int row = c >> 2, seg = (c & 3) * 8;
            gl2lds16(&A[(size_t)(m0 + row) * lda + k0 + seg], &a_lds[buf][c * 8]);
            gl2lds16(&Bt[(size_t)(n0 + row) * K + k0 + seg], &b_lds[buf][c * 8]);
        }
    };

    int nt = K >> 5;
    stage(0, 0);
    __syncthreads();                          // buf0 ready
    for (int t = 0; t < nt; t++) {
        int buf = t & 1;
        if (t + 1 < nt) stage((t + 1) * 32, buf ^ 1);   // flies under MFMA(t)
        short8 af[4], bfr[4];
#pragma unroll
        for (int i = 0; i < 4; i++)
            af[i] = *(const short8*)(&a_lds[buf][(wm + i * 16 + lr) * 32 + lk]);
#pragma unroll
        for (int j = 0; j < 4; j++)
            bfr[j] = *(const short8*)(&b_lds[buf][(wn + j * 16 + lr) * 32 + lk]);
#pragma unroll
        for (int i = 0; i < 4; i++)
#pragma unroll
            for (int j = 0; j < 4; j++)
                acc[i][j] = MFMA16(af[i], bfr[j], acc[i][j]);
        __syncthreads();                      // drains vmcnt -> buf^1 ready
    }
#pragma unroll
    for (int i = 0; i < 4; i++)
#pragma unroll
        for (int j = 0; j < 4; j++)
#pragma unroll
            for (int r = 0; r < 4; r++) {
                int row = m0 + wm + i * 16 + quad * 4 + r;
                int col = n0 + wn + j * 16 + lr;
                if (OUTF32)
                    ((float*)Co)[(size_t)row * ldc + col] = acc[i][j][r];
                else
                    ((unsigned short*)Co)[(size_t)row * ldc + col] = f2bf(acc[i][j][r]);
            }
}

// ---------------------------------------------------------------------------
// attention core: TWO 16-q-row groups (A: rows qrow0.., B: rows qrow0+16..)
// vs one 64-key staged tile. Every kb/vb LDS read feeds both groups' MFMAs.
// K LDS swizzle: chunk' = chunk ^ (key&15). V: chunk ^ (d&7). P rows [72].
// l comes from PV MFMA vs the ones-row (V^T row 128) — no rsum shuffles.
// ---------------------------------------------------------------------------
__device__ __forceinline__ void attn_core_pair(
        const short8 (&qfA)[4], const short8 (&qfB)[4],
        floatx4 (&oA)[8], floatx4 (&oB)[8], floatx4& olA, floatx4& olB,
        float (&mA)[4], float (&mB)[4],
        const unsigned short* kb_lds, const unsigned short* vb_lds,
        unsigned short* p_w,
        int qrow0, int tk0, int lr, int quad, int lk) {
    floatx4 zero4 = {0.f, 0.f, 0.f, 0.f};
    const float scale = 0.08838834764831845f;

    floatx4 sA[4], sB[4];
#pragma unroll
    for (int n = 0; n < 4; n++) {
        sA[n] = zero4; sB[n] = zero4;
#pragma unroll
        for (int c = 0; c < 4; c++) {
            short8 kb = *(const short8*)(
                &kb_lds[(n * 16 + lr) * 128 + (((c * 4 + quad) ^ lr) * 8)]);
            sA[n] = MFMA16(qfA[c], kb, sA[n]);
            sB[n] = MFMA16(qfB[c], kb, sB[n]);
        }
    }

    float rmaxA[4], rmaxB[4];
#pragma unroll
    for (int r = 0; r < 4; r++) {
        int tqA = qrow0 + quad * 4 + r;
        int tqB = tqA + 16;
        float mxA = -1e30f, mxB = -1e30f;
#pragma unroll
        for (int n = 0; n < 4; n++) {
            int tk = tk0 + n * 16 + lr;
            float svA = sA[n][r] * scale;
            float svB = sB[n][r] * scale;
            svA = (tk > tqA) ? -1e30f : svA;
            svB = (tk > tqB) ? -1e30f : svB;
            sA[n][r] = svA; sB[n][r] = svB;
            mxA = fmaxf(mxA, svA); mxB = fmaxf(mxB, svB);
        }
        rmaxA[r] = mxA; rmaxB[r] = mxB;
    }
#pragma unroll
    for (int off = 1; off < 16; off <<= 1)
#pragma unroll
        for (int r = 0; r < 4; r++) {
            rmaxA[r] = fmaxf(rmaxA[r], __shfl_xor(rmaxA[r], off, 64));
            rmaxB[r] = fmaxf(rmaxB[r], __shfl_xor(rmaxB[r], off, 64));
        }

    float alphaA[4], alphaB[4];
#pragma unroll
    for (int r = 0; r < 4; r++) {
        float mnA = fmaxf(mA[r], rmaxA[r]);
        float mnB = fmaxf(mB[r], rmaxB[r]);
        alphaA[r] = __expf(mA[r] - mnA); mA[r] = mnA;
        alphaB[r] = __expf(mB[r] - mnB); mB[r] = mnB;
    }
#pragma unroll
    for (int n = 0; n < 4; n++)
#pragma unroll
        for (int r = 0; r < 4; r++) {
            float pA = __expf(sA[n][r] - mA[r]);
            float pB = __expf(sB[n][r] - mB[r]);
            p_w[(quad * 4 + r) * 72 + n * 16 + lr] = f2bf(pA);
            p_w[(16 + quad * 4 + r) * 72 + n * 16 + lr] = f2bf(pB);
        }

#pragma unroll
    for (int dt = 0; dt < 8; dt++)
#pragma unroll
        for (int r = 0; r < 4; r++) {
            oA[dt][r] *= alphaA[r];
            oB[dt][r] *= alphaB[r];
        }
#pragma unroll
    for (int r = 0; r < 4; r++) { olA[r] *= alphaA[r]; olB[r] *= alphaB[r]; }

    short8 paA[2], paB[2];
#pragma unroll
    for (int kc = 0; kc < 2; kc++) {
        paA[kc] = *(const short8*)(&p_w[lr * 72 + kc * 32 + lk]);
        paB[kc] = *(const short8*)(&p_w[(16 + lr) * 72 + kc * 32 + lk]);
    }
#pragma unroll
    for (int dt = 0; dt < 8; dt++) {
#pragma unroll
        for (int kc = 0; kc < 2; kc++) {
            short8 vb = *(const short8*)(
                &vb_lds[(dt * 16 + lr) * 64 + (((kc * 4 + quad) ^ (lr & 7)) * 8)]);
            oA[dt] = MFMA16(paA[kc], vb, oA[dt]);
            oB[dt] = MFMA16(paB[kc], vb, oB[dt]);
        }
    }
#pragma unroll
    for (int kc = 0; kc < 2; kc++) {
        short8 vb1 = *(const short8*)(&vb_lds[128 * 64 + (kc * 4 + quad) * 8]);
        olA = MFMA16(paA[kc], vb1, olA);
        olB = MFMA16(paB[kc], vb1, olB);
    }
}

// ------ flash attention: 128 q-rows/block, 4 waves x 32 rows, 64-key tiles --
__global__ __launch_bounds__(256, 2) void attn_fast(unsigned short* qkv,
                                                    const unsigned short* __restrict__ VT) {
    const int T = 2048, Cc = 2048, Dd = 128;
    // balanced map: consecutive blocks pair heavy+light (sum ~const).
    int xx = blockIdx.x;
    int qt = (xx & 1) ? (xx >> 1) : (15 - (xx >> 1));
    int bh = blockIdx.y;
    int b = bh >> 4, h = bh & 15;
    int tid = threadIdx.x, lane = tid & 63, w = tid >> 6;   // w in [0,4)
    int lr = lane & 15, quad = lane >> 4, lk = quad * 8;
    int t0 = qt * 128;
    int wrow = t0 + w * 32;                    // this wave's first q-row

    __shared__ __align__(16) unsigned short k_lds[64 * 128];    // [key][d] swz
    __shared__ __align__(16) unsigned short v_lds[129 * 64];    // [d][key] swz + ones
    __shared__ __align__(16) unsigned short p_lds[4][32][72];   // per-wave P

    if (tid < 64) v_lds[128 * 64 + tid] = 0x3F80;   // bf16 1.0 ones-row

    short8 qfA[4], qfB[4];
    {
        size_t qrA = (size_t)(b * T + wrow + lr) * 3 * Cc + h * Dd;
        size_t qrB = (size_t)(b * T + wrow + 16 + lr) * 3 * Cc + h * Dd;
#pragma unroll
        for (int c = 0; c < 4; c++) {
            qfA[c] = *(const short8*)(&qkv[qrA + c * 32 + lk]);
            qfB[c] = *(const short8*)(&qkv[qrB + c * 32 + lk]);
        }
    }

    floatx4 oA[8], oB[8];
    floatx4 zero4 = {0.f, 0.f, 0.f, 0.f};
#pragma unroll
    for (int i = 0; i < 8; i++) { oA[i] = zero4; oB[i] = zero4; }
    floatx4 olA = zero4, olB = zero4;
    float mA[4], mB[4];
#pragma unroll
    for (int r = 0; r < 4; r++) { mA[r] = -1e30f; mB[r] = -1e30f; }

    // staging geometry (per thread: 4 K chunks + 4 V chunks of 16B)
    int krow[4], kslot[4], vrow[4], vslot[4];
#pragma unroll
    for (int i = 0; i < 4; i++) {
        int c = i * 256 + tid;
        krow[i] = c >> 4; kslot[i] = c & 15;       // K: 64 rows x 16 chunks
        vrow[i] = c >> 3; vslot[i] = c & 7;        // V: 128 rows x 8 chunks
    }
    uint4v kA[4], vA[4];
    auto gload = [&](int kt) {
        int tk0 = kt * 64;
#pragma unroll
        for (int i = 0; i < 4; i++) {
            kA[i] = *(const uint4v*)(
                &qkv[((size_t)(b * T + tk0 + krow[i]) * 3 + 1) * Cc + h * Dd + kslot[i] * 8]);
            vA[i] = *(const uint4v*)(
                &VT[((size_t)bh * Dd + vrow[i]) * T + tk0 + vslot[i] * 8]);
        }
    };
    auto lwrite = [&]() {
#pragma unroll
        for (int i = 0; i < 4; i++) {
            *(uint4v*)(&k_lds[krow[i] * 128 + ((kslot[i] ^ (krow[i] & 15)) * 8)]) = kA[i];
            *(uint4v*)(&v_lds[vrow[i] * 64 + ((vslot[i] ^ (vrow[i] & 7)) * 8)]) = vA[i];
        }
    };

    int nkt = 2 * qt + 2;
    gload(0);

    for (int kt = 0; kt < nkt; kt++) {
        lwrite();                                  // vmcnt waited by dependence
        bar_lds_only();                            // LDS tile ready (no vm drain)
        if (kt + 1 < nkt) gload(kt + 1);           // in flight across whole tile
        int tk0 = kt * 64;
        if (tk0 <= wrow + 31)                      // wave-uniform skip (grp B bound)
            attn_core_pair(qfA, qfB, oA, oB, olA, olB, mA, mB,
                           k_lds, v_lds, &p_lds[w][0][0], wrow, tk0, lr, quad, lk);
        bar_lds_only();                            // all reads of tile kt done
    }

    // epilogue: O over q slots -> qkv[b, t, 0, h, d]
#pragma unroll
    for (int dt = 0; dt < 8; dt++)
#pragma unroll
        for (int r = 0; r < 4; r++) {
            int col = dt * 16 + lr;
            int rowA = wrow + quad * 4 + r;
            int rowB = rowA + 16;
            qkv[(size_t)(b * T + rowA) * 3 * Cc + h * Dd + col] =
                f2bf(oA[dt][r] * (1.0f / olA[r]));
            qkv[(size_t)(b * T + rowB) * 3 * Cc + h * Dd + col] =
                f2bf(oB[dt][r] * (1.0f / olB[r]));
        }
}

// ---------------------------------------------------------------------------
extern "C" void kernel_launch(void* const* d_in, const int* in_sizes, int n_in,
                              void* d_out, int out_size, void* d_ws, size_t ws_size,
                              hipStream_t stream) {
    const float* x    = (const float*)d_in[0];
    const float* wqkv = (const float*)d_in[1];
    const float* wout = (const float*)d_in[2];
    const float* cosT = (const float*)d_in[3];
    const float* sinT = (const float*)d_in[4];
    float* out = (float*)d_out;

    unsigned short* qkv = (unsigned short*)d_ws;          // 48 MiB
    const size_t QKV = 25165824, XBF = 8388608;
    unsigned short* xbf = qkv + QKV;                      // 16 MiB; VT overlays after gemm1
    unsigned short* wTq = xbf + XBF;                      // 24 MiB; wTo overlays after gemm1
    unsigned short* VT  = xbf;
    unsigned short* wTo = wTq;

    cvt_k<<<4096, 256, 0, stream>>>(x, xbf, 8388608);
    transpose_f2b_k<<<dim3(192, 64), 256, 0, stream>>>(wqkv, wTq, 2048, 6144);
    gemm_bt<false><<<dim3(48, 32), 256, 0, stream>>>(xbf, 2048, wTq, qkv, 6144,
                                                     4096, 6144, 2048);
    rotary_k<<<32768, 256, 0, stream>>>(qkv, cosT, sinT);
    transpose_f2b_k<<<dim3(64, 64), 256, 0, stream>>>(wout, wTo, 2048, 2048);
    transpose_v_k<<<dim3(64, 4, 32), 256, 0, stream>>>(qkv, VT);
    attn_fast<<<dim3(16, 32), 256, 0, stream>>>(qkv, VT);
    gemm_bt<true><<<dim3(16, 32), 256, 0, stream>>>(qkv, 6144, wTo, out, 2048,
                                                    4096, 2048, 2048);
}